// Round 10
// baseline (412.309 us; speedup 1.0000x reference)
//
#include <hip/hip_runtime.h>
#include <math.h>

#define NN 50000
#define NE 800000
#define NG 50
#define F0 128
#define F1 64
#define F2 32
#define NPB 256                  // nodes per bucket (bucket = dst >> 8)
#define NBK 196                  // ceil(NN/NPB)
#define CHUNK 4096
#define NC 196                   // ceil(NE/CHUNK)
#define NTILE1 1563              // ceil(NN/32)
#define NTILE2 782               // ceil(NN/64)

__device__ __forceinline__ float lrelu(float v, float slope) {
    return v > 0.0f ? v : v * slope;
}
__device__ __forceinline__ float bf2f(unsigned short u) {
    return __uint_as_float(((unsigned int)u) << 16);
}
__device__ __forceinline__ unsigned short f2bf(float f) {
    unsigned int u = __float_as_uint(f);
    return (unsigned short)((u + 0x7FFFu + ((u >> 16) & 1u)) >> 16);  // RNE
}

// ==== k1: blocks [0,NC) = per-chunk dst-bucket histogram; rest = GEMM1 tiles.
// z1 stored as bf16 (halves gather traffic downstream); el/er fp32.
__global__ __launch_bounds__(256) void k1_hist_gemm1_kernel(
    const int* __restrict__ dst, int* __restrict__ hist,
    const float* __restrict__ x, const float* __restrict__ W,
    const float* __restrict__ al, const float* __restrict__ ar,
    unsigned short* __restrict__ z1b, float* __restrict__ el, float* __restrict__ er)
{
    __shared__ float Ws[F0 * F1];     // 32 KB (hist aliases this)
    __shared__ float xs[32][F0];      // 16 KB
    int tid = threadIdx.x;

    if (blockIdx.x < NC) {
        int* h = (int*)Ws;
        int c = blockIdx.x;
        if (tid < NBK) h[tid] = 0;
        __syncthreads();
        int e0 = c * CHUNK;
        int e1 = (e0 + CHUNK < NE) ? e0 + CHUNK : NE;
        for (int e = e0 + tid; e < e1; e += 256)
            atomicAdd(&h[dst[e] >> 8], 1);
        __syncthreads();
        if (tid < NBK) hist[tid * NC + c] = h[tid];
        return;
    }

    int r0 = (blockIdx.x - NC) * 32;
    {
        const float4* W4 = reinterpret_cast<const float4*>(W);
        float4* Ws4 = reinterpret_cast<float4*>(Ws);
        #pragma unroll
        for (int i = 0; i < 8; ++i) Ws4[tid + i * 256] = W4[tid + i * 256];
    }
    {
        float4 zero = {0.f, 0.f, 0.f, 0.f};
        #pragma unroll
        for (int i = 0; i < 4; ++i) {
            int s = tid + i * 256;
            int row = s >> 5, c4 = s & 31;
            int grow = r0 + row;
            float4 v = (grow < NN)
                ? reinterpret_cast<const float4*>(x)[(size_t)grow * 32 + c4] : zero;
            *reinterpret_cast<float4*>(&xs[row][c4 * 4]) = v;
        }
    }
    __syncthreads();
    int j = tid & 63, rg = tid >> 6;
    float acc[8] = {0.f, 0.f, 0.f, 0.f, 0.f, 0.f, 0.f, 0.f};
    for (int k4 = 0; k4 < F0 / 4; ++k4) {
        float w0 = Ws[(k4 * 4 + 0) * F1 + j];
        float w1 = Ws[(k4 * 4 + 1) * F1 + j];
        float w2 = Ws[(k4 * 4 + 2) * F1 + j];
        float w3 = Ws[(k4 * 4 + 3) * F1 + j];
        #pragma unroll
        for (int r = 0; r < 8; ++r) {
            float4 xv = *reinterpret_cast<const float4*>(&xs[rg * 8 + r][k4 * 4]);
            acc[r] = fmaf(xv.x, w0, fmaf(xv.y, w1, fmaf(xv.z, w2, fmaf(xv.w, w3, acc[r]))));
        }
    }
    float a_l = al[j], a_r = ar[j];
    #pragma unroll
    for (int r = 0; r < 8; ++r) {
        int row = r0 + rg * 8 + r;
        if (row < NN) z1b[(size_t)row * F1 + j] = f2bf(acc[r]);
        float pl = acc[r] * a_l, pr = acc[r] * a_r;
        #pragma unroll
        for (int mm = 1; mm < 64; mm <<= 1) {
            pl += __shfl_xor(pl, mm);
            pr += __shfl_xor(pr, mm);
        }
        if (j == 0 && row < NN) { el[row] = pl; er[row] = pr; }
    }
}

// ==== p2a: per-bucket exclusive scan over chunks (in place); bucket totals out
__global__ __launch_bounds__(256) void p2a_scan_kernel(
    int* __restrict__ hist, int* __restrict__ btot)
{
    __shared__ int t[256];
    int b = blockIdx.x;
    int v = (threadIdx.x < NC) ? hist[b * NC + threadIdx.x] : 0;
    t[threadIdx.x] = v;
    __syncthreads();
    for (int off = 1; off < 256; off <<= 1) {
        int u = (threadIdx.x >= off) ? t[threadIdx.x - off] : 0;
        __syncthreads();
        t[threadIdx.x] += u;
        __syncthreads();
    }
    if (threadIdx.x < NC) hist[b * NC + threadIdx.x] = t[threadIdx.x] - v; // exclusive
    if (threadIdx.x == 255) btot[b] = t[255];
}

// ==== p3: partition edges into bucket-contiguous (src,dst); bucket bases from btot
__global__ __launch_bounds__(256) void p3_part_kernel(
    const int* __restrict__ src, const int* __restrict__ dst,
    const int* __restrict__ hist, const int* __restrict__ btot,
    int2* __restrict__ part)
{
    __shared__ int t[256];
    __shared__ int base[NBK];
    __shared__ int cnt[NBK];
    int tid = threadIdx.x;
    int c = blockIdx.x;
    int v = (tid < NBK) ? btot[tid] : 0;
    t[tid] = v;
    __syncthreads();
    for (int off = 1; off < 256; off <<= 1) {
        int u = (tid >= off) ? t[tid - off] : 0;
        __syncthreads();
        t[tid] += u;
        __syncthreads();
    }
    if (tid < NBK) {
        base[tid] = hist[tid * NC + c] + (t[tid] - v);
        cnt[tid] = 0;
    }
    __syncthreads();
    int e0 = c * CHUNK;
    int e1 = (e0 + CHUNK < NE) ? e0 + CHUNK : NE;
    for (int e = e0 + tid; e < e1; e += 256) {
        int s = src[e], d = dst[e];
        int b = d >> 8;
        int r = atomicAdd(&cnt[b], 1);
        part[base[b] + r] = make_int2(s, d);
    }
}

// ==== p4: per-bucket rank -> row_start + srcs (dense region per block)
__global__ __launch_bounds__(256) void p4_fill_kernel(
    const int2* __restrict__ part, const int* __restrict__ btot,
    int* __restrict__ row_start, int* __restrict__ srcs)
{
    __shared__ int t[256];
    __shared__ int deg[NPB];
    __shared__ int off[NPB];
    __shared__ int cnt[NPB];
    int tid = threadIdx.x;
    int b = blockIdx.x;
    int v = (tid < NBK) ? btot[tid] : 0;
    t[tid] = v;
    __syncthreads();
    for (int o = 1; o < 256; o <<= 1) {
        int u = (tid >= o) ? t[tid - o] : 0;
        __syncthreads();
        t[tid] += u;
        __syncthreads();
    }
    int hi = t[b];
    int lo = hi - btot[b];
    if (b == 0 && tid == 0) row_start[NN] = NE;
    deg[tid] = 0;
    cnt[tid] = 0;
    __syncthreads();
    for (int i = lo + tid; i < hi; i += 256)
        atomicAdd(&deg[part[i].y & (NPB - 1)], 1);
    __syncthreads();
    int dv = deg[tid];
    off[tid] = dv;
    __syncthreads();
    for (int o = 1; o < 256; o <<= 1) {
        int u = (tid >= o) ? off[tid - o] : 0;
        __syncthreads();
        off[tid] += u;
        __syncthreads();
    }
    int ex = off[tid] - dv;
    __syncthreads();
    off[tid] = ex;
    __syncthreads();
    int node = b * NPB + tid;
    if (node < NN) row_start[node] = lo + ex;
    for (int i = lo + tid; i < hi; i += 256) {
        int2 e = part[i];
        int n = e.y & (NPB - 1);
        int r = atomicAdd(&cnt[n], 1);
        srcs[lo + off[n] + r] = e.x;
    }
}

// ==== fused: GAT layer-1 aggregation (64 nodes/block, h1 tile in LDS) + GEMM2.
// Layer-2 logits to el2/er2 (separate buffers: other blocks still read el/er).
__global__ __launch_bounds__(256) void fused_agg1_gemm2_kernel(
    const int* __restrict__ row_start, const int* __restrict__ srcs,
    const float* __restrict__ el, const float* __restrict__ er,
    const unsigned short* __restrict__ z1b, const float* __restrict__ b1,
    const float* __restrict__ W2, const float* __restrict__ al2,
    const float* __restrict__ ar2,
    unsigned short* __restrict__ z2b, float* __restrict__ el2, float* __restrict__ er2)
{
    __shared__ float Ws[F1 * F2];     // 8 KB
    __shared__ float hs[64][F1];      // 16 KB h1 tile
    int tid = threadIdx.x;
    int r0 = blockIdx.x * 64;

    {   // stage W2 (agg phase doesn't touch Ws; gemm phase is after the sync)
        const float4* W4 = reinterpret_cast<const float4*>(W2);
        float4* Ws4 = reinterpret_cast<float4*>(Ws);
        #pragma unroll
        for (int i = 0; i < 2; ++i) Ws4[tid + i * 256] = W4[tid + i * 256];
    }

    // ---- agg phase: wave w handles nodes r0 + it*4 + w, it = 0..15
    int lane = tid & 63;
    int w = tid >> 6;
    int g = lane >> 4, c = lane & 15;
    const ushort4* z4 = reinterpret_cast<const ushort4*>(z1b);

    for (int it = 0; it < 16; ++it) {
        int node = r0 + it * 4 + w;
        int trow = it * 4 + w;
        if (node < NN) {
            int beg = row_start[node], end = row_start[node + 1];
            float erd = er[node];
            int i0 = beg + lane;
            float v0 = -INFINITY;
            if (i0 < end) v0 = lrelu(el[srcs[i0]] + erd, 0.2f);
            float lm = v0;
            for (int i = i0 + 64; i < end; i += 64)
                lm = fmaxf(lm, lrelu(el[srcs[i]] + erd, 0.2f));
            #pragma unroll
            for (int mm = 1; mm < 64; mm <<= 1) lm = fmaxf(lm, __shfl_xor(lm, mm));

            float preg = 0.f, ls = 0.f;
            if (i0 < end) { preg = __expf(v0 - lm); ls = preg; }
            for (int i = i0 + 64; i < end; i += 64)
                ls += __expf(lrelu(el[srcs[i]] + erd, 0.2f) - lm);
            #pragma unroll
            for (int mm = 1; mm < 64; mm <<= 1) ls += __shfl_xor(ls, mm);
            float inv_s = (ls > 0.f) ? 1.0f / ls : 0.f;
            preg *= inv_s;

            float4 acc = {0.f, 0.f, 0.f, 0.f};
            int ib = beg;
            for (; ib + 8 <= end; ib += 8) {
                int ia = ib + g, ic = ib + 4 + g;
                int ja = ia - beg, jc = ic - beg;
                float aa = __shfl(preg, ja & 63);
                float ac = __shfl(preg, jc & 63);
                int sna = srcs[ia], snc = srcs[ic];
                if (ja >= 64) aa = __expf(lrelu(el[sna] + erd, 0.2f) - lm) * inv_s;
                if (jc >= 64) ac = __expf(lrelu(el[snc] + erd, 0.2f) - lm) * inv_s;
                ushort4 ua = z4[(size_t)sna * 16 + c];
                ushort4 uc = z4[(size_t)snc * 16 + c];
                acc.x = fmaf(aa, bf2f(ua.x), fmaf(ac, bf2f(uc.x), acc.x));
                acc.y = fmaf(aa, bf2f(ua.y), fmaf(ac, bf2f(uc.y), acc.y));
                acc.z = fmaf(aa, bf2f(ua.z), fmaf(ac, bf2f(uc.z), acc.z));
                acc.w = fmaf(aa, bf2f(ua.w), fmaf(ac, bf2f(uc.w), acc.w));
            }
            for (; ib < end; ib += 4) {
                int i = ib + g, jj = i - beg;
                float aa = __shfl(preg, jj & 63);
                if (i < end) {
                    int sn = srcs[i];
                    if (jj >= 64) aa = __expf(lrelu(el[sn] + erd, 0.2f) - lm) * inv_s;
                    ushort4 u = z4[(size_t)sn * 16 + c];
                    acc.x = fmaf(aa, bf2f(u.x), acc.x);
                    acc.y = fmaf(aa, bf2f(u.y), acc.y);
                    acc.z = fmaf(aa, bf2f(u.z), acc.z);
                    acc.w = fmaf(aa, bf2f(u.w), acc.w);
                }
            }
            #pragma unroll
            for (int mm = 16; mm < 64; mm <<= 1) {
                acc.x += __shfl_xor(acc.x, mm);
                acc.y += __shfl_xor(acc.y, mm);
                acc.z += __shfl_xor(acc.z, mm);
                acc.w += __shfl_xor(acc.w, mm);
            }
            if (g == 0) {
                float4 bb = reinterpret_cast<const float4*>(b1)[c];
                float4 o;
                o.x = lrelu(acc.x + bb.x, 0.01f);
                o.y = lrelu(acc.y + bb.y, 0.01f);
                o.z = lrelu(acc.z + bb.z, 0.01f);
                o.w = lrelu(acc.w + bb.w, 0.01f);
                *reinterpret_cast<float4*>(&hs[trow][c * 4]) = o;
            }
        } else if (g == 0) {
            float4 zero = {0.f, 0.f, 0.f, 0.f};
            *reinterpret_cast<float4*>(&hs[trow][c * 4]) = zero;
        }
    }
    __syncthreads();

    // ---- gemm2 phase on the LDS tile
    int j = tid & 31, rg = tid >> 5;
    float acc[8] = {0.f, 0.f, 0.f, 0.f, 0.f, 0.f, 0.f, 0.f};
    for (int k4 = 0; k4 < F1 / 4; ++k4) {
        float w0 = Ws[(k4 * 4 + 0) * F2 + j];
        float w1 = Ws[(k4 * 4 + 1) * F2 + j];
        float w2 = Ws[(k4 * 4 + 2) * F2 + j];
        float w3 = Ws[(k4 * 4 + 3) * F2 + j];
        #pragma unroll
        for (int r = 0; r < 8; ++r) {
            float4 xv = *reinterpret_cast<const float4*>(&hs[rg * 8 + r][k4 * 4]);
            acc[r] = fmaf(xv.x, w0, fmaf(xv.y, w1, fmaf(xv.z, w2, fmaf(xv.w, w3, acc[r]))));
        }
    }
    float a_l = al2[j], a_r = ar2[j];
    #pragma unroll
    for (int r = 0; r < 8; ++r) {
        int row = r0 + rg * 8 + r;
        if (row < NN) z2b[(size_t)row * F2 + j] = f2bf(acc[r]);
        float pl = acc[r] * a_l, pr = acc[r] * a_r;
        #pragma unroll
        for (int mm = 1; mm < 32; mm <<= 1) {
            pl += __shfl_xor(pl, mm);
            pr += __shfl_xor(pr, mm);
        }
        if (j == 0 && row < NN) { el2[row] = pl; er2[row] = pr; }
    }
}

// ==== GAT layer-2 aggregation (half-wave/node, bf16 z2, 8 edges in flight)
__global__ __launch_bounds__(256) void gat_agg32_kernel(
    const int* __restrict__ row_start, const int* __restrict__ srcs,
    const float* __restrict__ el, const float* __restrict__ er,
    const unsigned short* __restrict__ z2b, const float* __restrict__ b,
    float* __restrict__ out, float slope_out)
{
    int node = (blockIdx.x * 256 + threadIdx.x) >> 5;
    if (node >= NN) return;
    int sub = threadIdx.x & 31;
    int base = threadIdx.x & 32;
    int g = sub >> 3, c = sub & 7;
    int beg = row_start[node], end = row_start[node + 1];
    float erd = er[node];

    int i0 = beg + sub;
    float v0 = -INFINITY;
    if (i0 < end) v0 = lrelu(el[srcs[i0]] + erd, 0.2f);
    float lm = v0;
    for (int i = i0 + 32; i < end; i += 32)
        lm = fmaxf(lm, lrelu(el[srcs[i]] + erd, 0.2f));
    #pragma unroll
    for (int mm = 1; mm < 32; mm <<= 1) lm = fmaxf(lm, __shfl_xor(lm, mm));

    float preg = 0.f, ls = 0.f;
    if (i0 < end) { preg = __expf(v0 - lm); ls = preg; }
    for (int i = i0 + 32; i < end; i += 32)
        ls += __expf(lrelu(el[srcs[i]] + erd, 0.2f) - lm);
    #pragma unroll
    for (int mm = 1; mm < 32; mm <<= 1) ls += __shfl_xor(ls, mm);
    float inv_s = (ls > 0.f) ? 1.0f / ls : 0.f;
    preg *= inv_s;

    const ushort4* z4 = reinterpret_cast<const ushort4*>(z2b);
    float4 acc = {0.f, 0.f, 0.f, 0.f};
    int ib = beg;
    for (; ib + 8 <= end; ib += 8) {
        int ia = ib + g, ic = ib + 4 + g;
        int ja = ia - beg, jc = ic - beg;
        float aa = __shfl(preg, base | (ja & 31));
        float ac = __shfl(preg, base | (jc & 31));
        int sna = srcs[ia], snc = srcs[ic];
        if (ja >= 32) aa = __expf(lrelu(el[sna] + erd, 0.2f) - lm) * inv_s;
        if (jc >= 32) ac = __expf(lrelu(el[snc] + erd, 0.2f) - lm) * inv_s;
        ushort4 ua = z4[(size_t)sna * 8 + c];
        ushort4 uc = z4[(size_t)snc * 8 + c];
        acc.x = fmaf(aa, bf2f(ua.x), fmaf(ac, bf2f(uc.x), acc.x));
        acc.y = fmaf(aa, bf2f(ua.y), fmaf(ac, bf2f(uc.y), acc.y));
        acc.z = fmaf(aa, bf2f(ua.z), fmaf(ac, bf2f(uc.z), acc.z));
        acc.w = fmaf(aa, bf2f(ua.w), fmaf(ac, bf2f(uc.w), acc.w));
    }
    for (; ib < end; ib += 4) {
        int i = ib + g, jj = i - beg;
        float aa = __shfl(preg, base | (jj & 31));
        if (i < end) {
            int sn = srcs[i];
            if (jj >= 32) aa = __expf(lrelu(el[sn] + erd, 0.2f) - lm) * inv_s;
            ushort4 u = z4[(size_t)sn * 8 + c];
            acc.x = fmaf(aa, bf2f(u.x), acc.x);
            acc.y = fmaf(aa, bf2f(u.y), acc.y);
            acc.z = fmaf(aa, bf2f(u.z), acc.z);
            acc.w = fmaf(aa, bf2f(u.w), acc.w);
        }
    }
    #pragma unroll
    for (int mm = 8; mm < 32; mm <<= 1) {
        acc.x += __shfl_xor(acc.x, mm);
        acc.y += __shfl_xor(acc.y, mm);
        acc.z += __shfl_xor(acc.z, mm);
        acc.w += __shfl_xor(acc.w, mm);
    }
    if (g == 0) {
        float4 bb = reinterpret_cast<const float4*>(b)[c];
        float4 o;
        o.x = lrelu(acc.x + bb.x, slope_out);
        o.y = lrelu(acc.y + bb.y, slope_out);
        o.z = lrelu(acc.z + bb.z, slope_out);
        o.w = lrelu(acc.w + bb.w, slope_out);
        reinterpret_cast<float4*>(out)[(size_t)node * 8 + c] = o;
    }
}

// ==== per-graph mean pool (graph_id sorted); one block per graph
__global__ __launch_bounds__(256) void pool_kernel(
    const float* __restrict__ h2, const int* __restrict__ gid, float* __restrict__ out)
{
    int g = blockIdx.x;
    int lo = 0, hi = NN;
    while (lo < hi) { int mid = (lo + hi) >> 1; if (gid[mid] < g) lo = mid + 1; else hi = mid; }
    int start = lo;
    hi = NN;
    while (lo < hi) { int mid = (lo + hi) >> 1; if (gid[mid] < g + 1) lo = mid + 1; else hi = mid; }
    int end = lo;
    int f = threadIdx.x & 31, r = threadIdx.x >> 5;
    float acc = 0.f;
    for (int n = start + r; n < end; n += 8) acc += h2[(size_t)n * F2 + f];
    __shared__ float red[256];
    red[threadIdx.x] = acc;
    __syncthreads();
    for (int st = 128; st >= 32; st >>= 1) {
        if (threadIdx.x < st) red[threadIdx.x] += red[threadIdx.x + st];
        __syncthreads();
    }
    if (threadIdx.x < 32) {
        float cnt = (float)(end - start);
        out[g * F2 + threadIdx.x] = red[threadIdx.x] / fmaxf(cnt, 1.0f);
    }
}

extern "C" void kernel_launch(void* const* d_in, const int* in_sizes, int n_in,
                              void* d_out, int out_size, void* d_ws, size_t ws_size,
                              hipStream_t stream)
{
    const float* x   = (const float*)d_in[0];
    const int*   src = (const int*)d_in[1];
    const int*   dst = (const int*)d_in[2];
    const int*   gid = (const int*)d_in[3];
    const float* W1  = (const float*)d_in[4];
    const float* al1 = (const float*)d_in[5];
    const float* ar1 = (const float*)d_in[6];
    const float* b1  = (const float*)d_in[7];
    const float* W2  = (const float*)d_in[8];
    const float* al2 = (const float*)d_in[9];
    const float* ar2 = (const float*)d_in[10];
    const float* b2  = (const float*)d_in[11];
    float* out = (float*)d_out;

    float* ws = (float*)d_ws;
    unsigned short* z1b = (unsigned short*)ws;             // NN*64 bf16 = NN*32 f
    unsigned short* z2b = (unsigned short*)(ws + (size_t)NN * 32); // NN*32 bf16
    float* h2   = ws + (size_t)NN * 32 + (size_t)NN * 16;  // NN*32 floats
    float* el   = h2 + (size_t)NN * F2;                    // NN
    float* er   = el + NN;                                 // NN
    float* el2  = er + NN;                                 // NN
    float* er2  = el2 + NN;                                // NN
    int* row_start = (int*)(er2 + NN);                     // NN+1 (+1 pad)
    int* srcs      = row_start + NN + 2;                   // NE (even offset kept)
    int* hist      = srcs + NE;                            // NBK*NC
    int* btot      = hist + NBK * NC;                      // NBK (+2 pad)
    int2* part     = (int2*)(btot + NBK + 2);              // NE int2

    // d1: per-chunk histogram (blocks 0..NC-1) || GEMM1 (blocks NC..)
    k1_hist_gemm1_kernel<<<NC + NTILE1, 256, 0, stream>>>(
        dst, hist, x, W1, al1, ar1, z1b, el, er);
    // d2: per-bucket exclusive scan over chunks
    p2a_scan_kernel<<<NBK, 256, 0, stream>>>(hist, btot);
    // d3: partition into bucket-contiguous (src,dst)
    p3_part_kernel<<<NC, 256, 0, stream>>>(src, dst, hist, btot, part);
    // d4: per-bucket rank -> row_start + srcs
    p4_fill_kernel<<<NBK, 256, 0, stream>>>(part, btot, row_start, srcs);
    // d5: fused GAT layer-1 aggregation + GEMM2 (h1 lives in LDS only)
    fused_agg1_gemm2_kernel<<<NTILE2, 256, 0, stream>>>(
        row_start, srcs, el, er, z1b, b1, W2, al2, ar2, z2b, el2, er2);
    // d6: GAT layer-2 aggregation
    gat_agg32_kernel<<<(NN * 32 + 255) / 256, 256, 0, stream>>>(
        row_start, srcs, el2, er2, z2b, b2, h2, 0.01f);
    // d7: per-graph mean pool
    pool_kernel<<<NG, 256, 0, stream>>>(h2, gid, out);
}

// Round 11
// 269.470 us; speedup vs baseline: 1.5301x; 1.5301x over previous
//
#include <hip/hip_runtime.h>
#include <math.h>

#define NN 50000
#define NE 800000
#define NG 50
#define F0 128
#define F1 64
#define F2 32
#define NPB 256                  // nodes per bucket (bucket = dst >> 8)
#define NBK 196                  // ceil(NN/NPB)
#define CHUNK 4096
#define NC 196                   // ceil(NE/CHUNK)
#define NTILE1 1563              // ceil(NN/32)
#define NTILE2 782               // ceil(NN/64)

__device__ __forceinline__ float lrelu(float v, float slope) {
    return v > 0.0f ? v : v * slope;
}
__device__ __forceinline__ float bf2f(unsigned short u) {
    return __uint_as_float(((unsigned int)u) << 16);
}
__device__ __forceinline__ unsigned short f2bf(float f) {
    unsigned int u = __float_as_uint(f);
    return (unsigned short)((u + 0x7FFFu + ((u >> 16) & 1u)) >> 16);  // RNE
}

// ==== k1: blocks [0,NC) = per-chunk dst-bucket histogram; rest = GEMM1 tiles.
__global__ __launch_bounds__(256) void k1_hist_gemm1_kernel(
    const int* __restrict__ dst, int* __restrict__ hist,
    const float* __restrict__ x, const float* __restrict__ W,
    const float* __restrict__ al, const float* __restrict__ ar,
    unsigned short* __restrict__ z1b, float* __restrict__ el, float* __restrict__ er)
{
    __shared__ float Ws[F0 * F1];     // 32 KB (hist aliases this)
    __shared__ float xs[32][F0];      // 16 KB
    int tid = threadIdx.x;

    if (blockIdx.x < NC) {
        int* h = (int*)Ws;
        int c = blockIdx.x;
        if (tid < NBK) h[tid] = 0;
        __syncthreads();
        int e0 = c * CHUNK;
        int e1 = (e0 + CHUNK < NE) ? e0 + CHUNK : NE;
        for (int e = e0 + tid; e < e1; e += 256)
            atomicAdd(&h[dst[e] >> 8], 1);
        __syncthreads();
        if (tid < NBK) hist[tid * NC + c] = h[tid];
        return;
    }

    int r0 = (blockIdx.x - NC) * 32;
    {
        const float4* W4 = reinterpret_cast<const float4*>(W);
        float4* Ws4 = reinterpret_cast<float4*>(Ws);
        #pragma unroll
        for (int i = 0; i < 8; ++i) Ws4[tid + i * 256] = W4[tid + i * 256];
    }
    {
        float4 zero = {0.f, 0.f, 0.f, 0.f};
        #pragma unroll
        for (int i = 0; i < 4; ++i) {
            int s = tid + i * 256;
            int row = s >> 5, c4 = s & 31;
            int grow = r0 + row;
            float4 v = (grow < NN)
                ? reinterpret_cast<const float4*>(x)[(size_t)grow * 32 + c4] : zero;
            *reinterpret_cast<float4*>(&xs[row][c4 * 4]) = v;
        }
    }
    __syncthreads();
    int j = tid & 63, rg = tid >> 6;
    float acc[8] = {0.f, 0.f, 0.f, 0.f, 0.f, 0.f, 0.f, 0.f};
    for (int k4 = 0; k4 < F0 / 4; ++k4) {
        float w0 = Ws[(k4 * 4 + 0) * F1 + j];
        float w1 = Ws[(k4 * 4 + 1) * F1 + j];
        float w2 = Ws[(k4 * 4 + 2) * F1 + j];
        float w3 = Ws[(k4 * 4 + 3) * F1 + j];
        #pragma unroll
        for (int r = 0; r < 8; ++r) {
            float4 xv = *reinterpret_cast<const float4*>(&xs[rg * 8 + r][k4 * 4]);
            acc[r] = fmaf(xv.x, w0, fmaf(xv.y, w1, fmaf(xv.z, w2, fmaf(xv.w, w3, acc[r]))));
        }
    }
    float a_l = al[j], a_r = ar[j];
    #pragma unroll
    for (int r = 0; r < 8; ++r) {
        int row = r0 + rg * 8 + r;
        if (row < NN) z1b[(size_t)row * F1 + j] = f2bf(acc[r]);
        float pl = acc[r] * a_l, pr = acc[r] * a_r;
        #pragma unroll
        for (int mm = 1; mm < 64; mm <<= 1) {
            pl += __shfl_xor(pl, mm);
            pr += __shfl_xor(pr, mm);
        }
        if (j == 0 && row < NN) { el[row] = pl; er[row] = pr; }
    }
}

// ==== p2a: per-bucket exclusive scan over chunks (in place); bucket totals out
__global__ __launch_bounds__(256) void p2a_scan_kernel(
    int* __restrict__ hist, int* __restrict__ btot)
{
    __shared__ int t[256];
    int b = blockIdx.x;
    int v = (threadIdx.x < NC) ? hist[b * NC + threadIdx.x] : 0;
    t[threadIdx.x] = v;
    __syncthreads();
    for (int off = 1; off < 256; off <<= 1) {
        int u = (threadIdx.x >= off) ? t[threadIdx.x - off] : 0;
        __syncthreads();
        t[threadIdx.x] += u;
        __syncthreads();
    }
    if (threadIdx.x < NC) hist[b * NC + threadIdx.x] = t[threadIdx.x] - v; // exclusive
    if (threadIdx.x == 255) btot[b] = t[255];
}

// ==== p3: partition edges into bucket-contiguous (src,dst)
__global__ __launch_bounds__(256) void p3_part_kernel(
    const int* __restrict__ src, const int* __restrict__ dst,
    const int* __restrict__ hist, const int* __restrict__ btot,
    int2* __restrict__ part)
{
    __shared__ int t[256];
    __shared__ int base[NBK];
    __shared__ int cnt[NBK];
    int tid = threadIdx.x;
    int c = blockIdx.x;
    int v = (tid < NBK) ? btot[tid] : 0;
    t[tid] = v;
    __syncthreads();
    for (int off = 1; off < 256; off <<= 1) {
        int u = (tid >= off) ? t[tid - off] : 0;
        __syncthreads();
        t[tid] += u;
        __syncthreads();
    }
    if (tid < NBK) {
        base[tid] = hist[tid * NC + c] + (t[tid] - v);
        cnt[tid] = 0;
    }
    __syncthreads();
    int e0 = c * CHUNK;
    int e1 = (e0 + CHUNK < NE) ? e0 + CHUNK : NE;
    for (int e = e0 + tid; e < e1; e += 256) {
        int s = src[e], d = dst[e];
        int b = d >> 8;
        int r = atomicAdd(&cnt[b], 1);
        part[base[b] + r] = make_int2(s, d);
    }
}

// ==== p4: per-bucket rank -> row_start + srcs
__global__ __launch_bounds__(256) void p4_fill_kernel(
    const int2* __restrict__ part, const int* __restrict__ btot,
    int* __restrict__ row_start, int* __restrict__ srcs)
{
    __shared__ int t[256];
    __shared__ int deg[NPB];
    __shared__ int off[NPB];
    __shared__ int cnt[NPB];
    int tid = threadIdx.x;
    int b = blockIdx.x;
    int v = (tid < NBK) ? btot[tid] : 0;
    t[tid] = v;
    __syncthreads();
    for (int o = 1; o < 256; o <<= 1) {
        int u = (tid >= o) ? t[tid - o] : 0;
        __syncthreads();
        t[tid] += u;
        __syncthreads();
    }
    int hi = t[b];
    int lo = hi - btot[b];
    if (b == 0 && tid == 0) row_start[NN] = NE;
    deg[tid] = 0;
    cnt[tid] = 0;
    __syncthreads();
    for (int i = lo + tid; i < hi; i += 256)
        atomicAdd(&deg[part[i].y & (NPB - 1)], 1);
    __syncthreads();
    int dv = deg[tid];
    off[tid] = dv;
    __syncthreads();
    for (int o = 1; o < 256; o <<= 1) {
        int u = (tid >= o) ? off[tid - o] : 0;
        __syncthreads();
        off[tid] += u;
        __syncthreads();
    }
    int ex = off[tid] - dv;
    __syncthreads();
    off[tid] = ex;
    __syncthreads();
    int node = b * NPB + tid;
    if (node < NN) row_start[node] = lo + ex;
    for (int i = lo + tid; i < hi; i += 256) {
        int2 e = part[i];
        int n = e.y & (NPB - 1);
        int r = atomicAdd(&cnt[n], 1);
        srcs[lo + off[n] + r] = e.x;
    }
}

// ==== GAT layer-1 aggregation (wave/node, bf16 z1, 8 edges in flight)
__global__ __launch_bounds__(256) void gat_agg64_kernel(
    const int* __restrict__ row_start, const int* __restrict__ srcs,
    const float* __restrict__ el, const float* __restrict__ er,
    const unsigned short* __restrict__ z1b, const float* __restrict__ b,
    float* __restrict__ out, float slope_out)
{
    int node = (blockIdx.x * 256 + threadIdx.x) >> 6;
    if (node >= NN) return;
    int lane = threadIdx.x & 63;
    int g = lane >> 4, c = lane & 15;
    int beg = row_start[node], end = row_start[node + 1];
    float erd = er[node];

    int i0 = beg + lane;
    float v0 = -INFINITY;
    if (i0 < end) v0 = lrelu(el[srcs[i0]] + erd, 0.2f);
    float lm = v0;
    for (int i = i0 + 64; i < end; i += 64)
        lm = fmaxf(lm, lrelu(el[srcs[i]] + erd, 0.2f));
    #pragma unroll
    for (int mm = 1; mm < 64; mm <<= 1) lm = fmaxf(lm, __shfl_xor(lm, mm));

    float preg = 0.f, ls = 0.f;
    if (i0 < end) { preg = __expf(v0 - lm); ls = preg; }
    for (int i = i0 + 64; i < end; i += 64)
        ls += __expf(lrelu(el[srcs[i]] + erd, 0.2f) - lm);
    #pragma unroll
    for (int mm = 1; mm < 64; mm <<= 1) ls += __shfl_xor(ls, mm);
    float inv_s = (ls > 0.f) ? 1.0f / ls : 0.f;
    preg *= inv_s;

    const ushort4* z4 = reinterpret_cast<const ushort4*>(z1b);
    float4 acc = {0.f, 0.f, 0.f, 0.f};
    int ib = beg;
    for (; ib + 8 <= end; ib += 8) {
        int ia = ib + g, ic = ib + 4 + g;
        int ja = ia - beg, jc = ic - beg;
        float aa = __shfl(preg, ja & 63);
        float ac = __shfl(preg, jc & 63);
        int sna = srcs[ia], snc = srcs[ic];
        if (ja >= 64) aa = __expf(lrelu(el[sna] + erd, 0.2f) - lm) * inv_s;
        if (jc >= 64) ac = __expf(lrelu(el[snc] + erd, 0.2f) - lm) * inv_s;
        ushort4 ua = z4[(size_t)sna * 16 + c];
        ushort4 uc = z4[(size_t)snc * 16 + c];
        acc.x = fmaf(aa, bf2f(ua.x), fmaf(ac, bf2f(uc.x), acc.x));
        acc.y = fmaf(aa, bf2f(ua.y), fmaf(ac, bf2f(uc.y), acc.y));
        acc.z = fmaf(aa, bf2f(ua.z), fmaf(ac, bf2f(uc.z), acc.z));
        acc.w = fmaf(aa, bf2f(ua.w), fmaf(ac, bf2f(uc.w), acc.w));
    }
    for (; ib < end; ib += 4) {
        int i = ib + g, jj = i - beg;
        float aa = __shfl(preg, jj & 63);
        if (i < end) {
            int sn = srcs[i];
            if (jj >= 64) aa = __expf(lrelu(el[sn] + erd, 0.2f) - lm) * inv_s;
            ushort4 u = z4[(size_t)sn * 16 + c];
            acc.x = fmaf(aa, bf2f(u.x), acc.x);
            acc.y = fmaf(aa, bf2f(u.y), acc.y);
            acc.z = fmaf(aa, bf2f(u.z), acc.z);
            acc.w = fmaf(aa, bf2f(u.w), acc.w);
        }
    }
    #pragma unroll
    for (int mm = 16; mm < 64; mm <<= 1) {
        acc.x += __shfl_xor(acc.x, mm);
        acc.y += __shfl_xor(acc.y, mm);
        acc.z += __shfl_xor(acc.z, mm);
        acc.w += __shfl_xor(acc.w, mm);
    }
    if (g == 0) {
        float4 bb = reinterpret_cast<const float4*>(b)[c];
        float4 o;
        o.x = lrelu(acc.x + bb.x, slope_out);
        o.y = lrelu(acc.y + bb.y, slope_out);
        o.z = lrelu(acc.z + bb.z, slope_out);
        o.w = lrelu(acc.w + bb.w, slope_out);
        reinterpret_cast<float4*>(out)[(size_t)node * 16 + c] = o;
    }
}

// ==== GEMM2: register-blocked 64-row tiles; h1 fp32 in, z2 bf16 out
__global__ __launch_bounds__(256) void gemm2_kernel(
    const float* __restrict__ h, const float* __restrict__ W,
    const float* __restrict__ al, const float* __restrict__ ar,
    unsigned short* __restrict__ z2b, float* __restrict__ el, float* __restrict__ er)
{
    __shared__ float Ws[F1 * F2];
    __shared__ float xs[64][F1];
    int tid = threadIdx.x;
    int r0 = blockIdx.x * 64;
    {
        const float4* W4 = reinterpret_cast<const float4*>(W);
        float4* Ws4 = reinterpret_cast<float4*>(Ws);
        #pragma unroll
        for (int i = 0; i < 2; ++i) Ws4[tid + i * 256] = W4[tid + i * 256];
    }
    {
        float4 zero = {0.f, 0.f, 0.f, 0.f};
        #pragma unroll
        for (int i = 0; i < 4; ++i) {
            int s = tid + i * 256;
            int row = s >> 4, c4 = s & 15;
            int grow = r0 + row;
            float4 v = (grow < NN)
                ? reinterpret_cast<const float4*>(h)[(size_t)grow * 16 + c4] : zero;
            *reinterpret_cast<float4*>(&xs[row][c4 * 4]) = v;
        }
    }
    __syncthreads();
    int j = tid & 31, rg = tid >> 5;
    float acc[8] = {0.f, 0.f, 0.f, 0.f, 0.f, 0.f, 0.f, 0.f};
    for (int k4 = 0; k4 < F1 / 4; ++k4) {
        float w0 = Ws[(k4 * 4 + 0) * F2 + j];
        float w1 = Ws[(k4 * 4 + 1) * F2 + j];
        float w2 = Ws[(k4 * 4 + 2) * F2 + j];
        float w3 = Ws[(k4 * 4 + 3) * F2 + j];
        #pragma unroll
        for (int r = 0; r < 8; ++r) {
            float4 xv = *reinterpret_cast<const float4*>(&xs[rg * 8 + r][k4 * 4]);
            acc[r] = fmaf(xv.x, w0, fmaf(xv.y, w1, fmaf(xv.z, w2, fmaf(xv.w, w3, acc[r]))));
        }
    }
    float a_l = al[j], a_r = ar[j];
    #pragma unroll
    for (int r = 0; r < 8; ++r) {
        int row = r0 + rg * 8 + r;
        if (row < NN) z2b[(size_t)row * F2 + j] = f2bf(acc[r]);
        float pl = acc[r] * a_l, pr = acc[r] * a_r;
        #pragma unroll
        for (int mm = 1; mm < 32; mm <<= 1) {
            pl += __shfl_xor(pl, mm);
            pr += __shfl_xor(pr, mm);
        }
        if (j == 0 && row < NN) { el[row] = pl; er[row] = pr; }
    }
}

// ==== GAT layer-2 aggregation (half-wave/node, bf16 z2, 8 edges in flight)
__global__ __launch_bounds__(256) void gat_agg32_kernel(
    const int* __restrict__ row_start, const int* __restrict__ srcs,
    const float* __restrict__ el, const float* __restrict__ er,
    const unsigned short* __restrict__ z2b, const float* __restrict__ b,
    float* __restrict__ out, float slope_out)
{
    int node = (blockIdx.x * 256 + threadIdx.x) >> 5;
    if (node >= NN) return;
    int sub = threadIdx.x & 31;
    int base = threadIdx.x & 32;
    int g = sub >> 3, c = sub & 7;
    int beg = row_start[node], end = row_start[node + 1];
    float erd = er[node];

    int i0 = beg + sub;
    float v0 = -INFINITY;
    if (i0 < end) v0 = lrelu(el[srcs[i0]] + erd, 0.2f);
    float lm = v0;
    for (int i = i0 + 32; i < end; i += 32)
        lm = fmaxf(lm, lrelu(el[srcs[i]] + erd, 0.2f));
    #pragma unroll
    for (int mm = 1; mm < 32; mm <<= 1) lm = fmaxf(lm, __shfl_xor(lm, mm));

    float preg = 0.f, ls = 0.f;
    if (i0 < end) { preg = __expf(v0 - lm); ls = preg; }
    for (int i = i0 + 32; i < end; i += 32)
        ls += __expf(lrelu(el[srcs[i]] + erd, 0.2f) - lm);
    #pragma unroll
    for (int mm = 1; mm < 32; mm <<= 1) ls += __shfl_xor(ls, mm);
    float inv_s = (ls > 0.f) ? 1.0f / ls : 0.f;
    preg *= inv_s;

    const ushort4* z4 = reinterpret_cast<const ushort4*>(z2b);
    float4 acc = {0.f, 0.f, 0.f, 0.f};
    int ib = beg;
    for (; ib + 8 <= end; ib += 8) {
        int ia = ib + g, ic = ib + 4 + g;
        int ja = ia - beg, jc = ic - beg;
        float aa = __shfl(preg, base | (ja & 31));
        float ac = __shfl(preg, base | (jc & 31));
        int sna = srcs[ia], snc = srcs[ic];
        if (ja >= 32) aa = __expf(lrelu(el[sna] + erd, 0.2f) - lm) * inv_s;
        if (jc >= 32) ac = __expf(lrelu(el[snc] + erd, 0.2f) - lm) * inv_s;
        ushort4 ua = z4[(size_t)sna * 8 + c];
        ushort4 uc = z4[(size_t)snc * 8 + c];
        acc.x = fmaf(aa, bf2f(ua.x), fmaf(ac, bf2f(uc.x), acc.x));
        acc.y = fmaf(aa, bf2f(ua.y), fmaf(ac, bf2f(uc.y), acc.y));
        acc.z = fmaf(aa, bf2f(ua.z), fmaf(ac, bf2f(uc.z), acc.z));
        acc.w = fmaf(aa, bf2f(ua.w), fmaf(ac, bf2f(uc.w), acc.w));
    }
    for (; ib < end; ib += 4) {
        int i = ib + g, jj = i - beg;
        float aa = __shfl(preg, base | (jj & 31));
        if (i < end) {
            int sn = srcs[i];
            if (jj >= 32) aa = __expf(lrelu(el[sn] + erd, 0.2f) - lm) * inv_s;
            ushort4 u = z4[(size_t)sn * 8 + c];
            acc.x = fmaf(aa, bf2f(u.x), acc.x);
            acc.y = fmaf(aa, bf2f(u.y), acc.y);
            acc.z = fmaf(aa, bf2f(u.z), acc.z);
            acc.w = fmaf(aa, bf2f(u.w), acc.w);
        }
    }
    #pragma unroll
    for (int mm = 8; mm < 32; mm <<= 1) {
        acc.x += __shfl_xor(acc.x, mm);
        acc.y += __shfl_xor(acc.y, mm);
        acc.z += __shfl_xor(acc.z, mm);
        acc.w += __shfl_xor(acc.w, mm);
    }
    if (g == 0) {
        float4 bb = reinterpret_cast<const float4*>(b)[c];
        float4 o;
        o.x = lrelu(acc.x + bb.x, slope_out);
        o.y = lrelu(acc.y + bb.y, slope_out);
        o.z = lrelu(acc.z + bb.z, slope_out);
        o.w = lrelu(acc.w + bb.w, slope_out);
        reinterpret_cast<float4*>(out)[(size_t)node * 8 + c] = o;
    }
}

// ==== per-graph mean pool (graph_id sorted); one block per graph
__global__ __launch_bounds__(256) void pool_kernel(
    const float* __restrict__ h2, const int* __restrict__ gid, float* __restrict__ out)
{
    int g = blockIdx.x;
    int lo = 0, hi = NN;
    while (lo < hi) { int mid = (lo + hi) >> 1; if (gid[mid] < g) lo = mid + 1; else hi = mid; }
    int start = lo;
    hi = NN;
    while (lo < hi) { int mid = (lo + hi) >> 1; if (gid[mid] < g + 1) lo = mid + 1; else hi = mid; }
    int end = lo;
    int f = threadIdx.x & 31, r = threadIdx.x >> 5;
    float acc = 0.f;
    for (int n = start + r; n < end; n += 8) acc += h2[(size_t)n * F2 + f];
    __shared__ float red[256];
    red[threadIdx.x] = acc;
    __syncthreads();
    for (int st = 128; st >= 32; st >>= 1) {
        if (threadIdx.x < st) red[threadIdx.x] += red[threadIdx.x + st];
        __syncthreads();
    }
    if (threadIdx.x < 32) {
        float cnt = (float)(end - start);
        out[g * F2 + threadIdx.x] = red[threadIdx.x] / fmaxf(cnt, 1.0f);
    }
}

extern "C" void kernel_launch(void* const* d_in, const int* in_sizes, int n_in,
                              void* d_out, int out_size, void* d_ws, size_t ws_size,
                              hipStream_t stream)
{
    const float* x   = (const float*)d_in[0];
    const int*   src = (const int*)d_in[1];
    const int*   dst = (const int*)d_in[2];
    const int*   gid = (const int*)d_in[3];
    const float* W1  = (const float*)d_in[4];
    const float* al1 = (const float*)d_in[5];
    const float* ar1 = (const float*)d_in[6];
    const float* b1  = (const float*)d_in[7];
    const float* W2  = (const float*)d_in[8];
    const float* al2 = (const float*)d_in[9];
    const float* ar2 = (const float*)d_in[10];
    const float* b2  = (const float*)d_in[11];
    float* out = (float*)d_out;

    float* ws = (float*)d_ws;
    unsigned short* z1b = (unsigned short*)ws;                    // NN*64 bf16 (= NN*32 floats)
    unsigned short* z2b = (unsigned short*)(ws + (size_t)NN * 32);// NN*32 bf16 (= NN*16 floats)
    float* h1   = ws + (size_t)NN * 32 + (size_t)NN * 16;         // NN*64 floats
    float* h2   = h1 + (size_t)NN * F1;                           // NN*32 floats
    float* el   = h2 + (size_t)NN * F2;                           // NN
    float* er   = el + NN;                                        // NN
    float* el2  = er + NN;                                        // NN
    float* er2  = el2 + NN;                                       // NN
    int* row_start = (int*)(er2 + NN);                            // NN+1 (+1 pad)
    int* srcs      = row_start + NN + 2;                          // NE
    int* hist      = srcs + NE;                                   // NBK*NC
    int* btot      = hist + NBK * NC;                             // NBK (+2 pad)
    int2* part     = (int2*)(btot + NBK + 2);                     // NE int2

    // d1: per-chunk histogram (blocks 0..NC-1) || GEMM1 (blocks NC..)
    k1_hist_gemm1_kernel<<<NC + NTILE1, 256, 0, stream>>>(
        dst, hist, x, W1, al1, ar1, z1b, el, er);
    // d2: per-bucket exclusive scan over chunks
    p2a_scan_kernel<<<NBK, 256, 0, stream>>>(hist, btot);
    // d3: partition into bucket-contiguous (src,dst)
    p3_part_kernel<<<NC, 256, 0, stream>>>(src, dst, hist, btot, part);
    // d4: per-bucket rank -> row_start + srcs
    p4_fill_kernel<<<NBK, 256, 0, stream>>>(part, btot, row_start, srcs);
    // d5: GAT layer-1 aggregation (bf16 z1)
    gat_agg64_kernel<<<(NN * 64 + 255) / 256, 256, 0, stream>>>(
        row_start, srcs, el, er, z1b, b1, h1, 0.01f);
    // d6: GEMM2 (h1 fp32 -> z2 bf16, el2/er2)
    gemm2_kernel<<<NTILE2, 256, 0, stream>>>(h1, W2, al2, ar2, z2b, el2, er2);
    // d7: GAT layer-2 aggregation (bf16 z2)
    gat_agg32_kernel<<<(NN * 32 + 255) / 256, 256, 0, stream>>>(
        row_start, srcs, el2, er2, z2b, b2, h2, 0.01f);
    // d8: per-graph mean pool
    pool_kernel<<<NG, 256, 0, stream>>>(h2, gid, out);
}

// Round 12
// 238.868 us; speedup vs baseline: 1.7261x; 1.1281x over previous
//
#include <hip/hip_runtime.h>
#include <math.h>

#define NN 50000
#define NE 800000
#define NG 50
#define F0 128
#define F1 64
#define F2 32
#define NPB 256                  // nodes per bucket (bucket = dst >> 8)
#define NBK 196                  // ceil(NN/NPB)
#define CHUNK 4096
#define NC 196                   // ceil(NE/CHUNK)
#define NTILE1 1563              // ceil(NN/32)

__device__ __forceinline__ float lrelu(float v, float slope) {
    return v > 0.0f ? v : v * slope;
}
__device__ __forceinline__ float bf2f(unsigned short u) {
    return __uint_as_float(((unsigned int)u) << 16);
}
__device__ __forceinline__ unsigned short f2bf(float f) {
    unsigned int u = __float_as_uint(f);
    return (unsigned short)((u + 0x7FFFu + ((u >> 16) & 1u)) >> 16);  // RNE
}

// ==== k1: blocks [0,NC) = per-chunk dst-bucket histogram; rest = GEMM1 tiles.
__global__ __launch_bounds__(256) void k1_hist_gemm1_kernel(
    const int* __restrict__ dst, int* __restrict__ hist,
    const float* __restrict__ x, const float* __restrict__ W,
    const float* __restrict__ al, const float* __restrict__ ar,
    unsigned short* __restrict__ z1b, float* __restrict__ el, float* __restrict__ er)
{
    __shared__ float Ws[F0 * F1];     // 32 KB (hist aliases this)
    __shared__ float xs[32][F0];      // 16 KB
    int tid = threadIdx.x;

    if (blockIdx.x < NC) {
        int* h = (int*)Ws;
        int c = blockIdx.x;
        if (tid < NBK) h[tid] = 0;
        __syncthreads();
        int e0 = c * CHUNK;
        int e1 = (e0 + CHUNK < NE) ? e0 + CHUNK : NE;
        for (int e = e0 + tid; e < e1; e += 256)
            atomicAdd(&h[dst[e] >> 8], 1);
        __syncthreads();
        if (tid < NBK) hist[tid * NC + c] = h[tid];
        return;
    }

    int r0 = (blockIdx.x - NC) * 32;
    {
        const float4* W4 = reinterpret_cast<const float4*>(W);
        float4* Ws4 = reinterpret_cast<float4*>(Ws);
        #pragma unroll
        for (int i = 0; i < 8; ++i) Ws4[tid + i * 256] = W4[tid + i * 256];
    }
    {
        float4 zero = {0.f, 0.f, 0.f, 0.f};
        #pragma unroll
        for (int i = 0; i < 4; ++i) {
            int s = tid + i * 256;
            int row = s >> 5, c4 = s & 31;
            int grow = r0 + row;
            float4 v = (grow < NN)
                ? reinterpret_cast<const float4*>(x)[(size_t)grow * 32 + c4] : zero;
            *reinterpret_cast<float4*>(&xs[row][c4 * 4]) = v;
        }
    }
    __syncthreads();
    int j = tid & 63, rg = tid >> 6;
    float acc[8] = {0.f, 0.f, 0.f, 0.f, 0.f, 0.f, 0.f, 0.f};
    for (int k4 = 0; k4 < F0 / 4; ++k4) {
        float w0 = Ws[(k4 * 4 + 0) * F1 + j];
        float w1 = Ws[(k4 * 4 + 1) * F1 + j];
        float w2 = Ws[(k4 * 4 + 2) * F1 + j];
        float w3 = Ws[(k4 * 4 + 3) * F1 + j];
        #pragma unroll
        for (int r = 0; r < 8; ++r) {
            float4 xv = *reinterpret_cast<const float4*>(&xs[rg * 8 + r][k4 * 4]);
            acc[r] = fmaf(xv.x, w0, fmaf(xv.y, w1, fmaf(xv.z, w2, fmaf(xv.w, w3, acc[r]))));
        }
    }
    float a_l = al[j], a_r = ar[j];
    #pragma unroll
    for (int r = 0; r < 8; ++r) {
        int row = r0 + rg * 8 + r;
        if (row < NN) z1b[(size_t)row * F1 + j] = f2bf(acc[r]);
        float pl = acc[r] * a_l, pr = acc[r] * a_r;
        #pragma unroll
        for (int mm = 1; mm < 64; mm <<= 1) {
            pl += __shfl_xor(pl, mm);
            pr += __shfl_xor(pr, mm);
        }
        if (j == 0 && row < NN) { el[row] = pl; er[row] = pr; }
    }
}

// ==== p2a: per-bucket exclusive scan over chunks (in place); bucket totals out
__global__ __launch_bounds__(256) void p2a_scan_kernel(
    int* __restrict__ hist, int* __restrict__ btot)
{
    __shared__ int t[256];
    int b = blockIdx.x;
    int v = (threadIdx.x < NC) ? hist[b * NC + threadIdx.x] : 0;
    t[threadIdx.x] = v;
    __syncthreads();
    for (int off = 1; off < 256; off <<= 1) {
        int u = (threadIdx.x >= off) ? t[threadIdx.x - off] : 0;
        __syncthreads();
        t[threadIdx.x] += u;
        __syncthreads();
    }
    if (threadIdx.x < NC) hist[b * NC + threadIdx.x] = t[threadIdx.x] - v; // exclusive
    if (threadIdx.x == 255) btot[b] = t[255];
}

// ==== p3: partition edges into bucket-contiguous packed entries
// entry = (src << 8) | (dst & 255)  (src < 2^16, so fits 24 bits)
__global__ __launch_bounds__(256) void p3_part_kernel(
    const int* __restrict__ src, const int* __restrict__ dst,
    const int* __restrict__ hist, const int* __restrict__ btot,
    unsigned int* __restrict__ part)
{
    __shared__ int t[256];
    __shared__ int base[NBK];
    __shared__ int cnt[NBK];
    int tid = threadIdx.x;
    int c = blockIdx.x;
    int v = (tid < NBK) ? btot[tid] : 0;
    t[tid] = v;
    __syncthreads();
    for (int off = 1; off < 256; off <<= 1) {
        int u = (tid >= off) ? t[tid - off] : 0;
        __syncthreads();
        t[tid] += u;
        __syncthreads();
    }
    if (tid < NBK) {
        base[tid] = hist[tid * NC + c] + (t[tid] - v);
        cnt[tid] = 0;
    }
    __syncthreads();
    int e0 = c * CHUNK;
    int e1 = (e0 + CHUNK < NE) ? e0 + CHUNK : NE;
    for (int e = e0 + tid; e < e1; e += 256) {
        int s = src[e], d = dst[e];
        int b = d >> 8;
        int r = atomicAdd(&cnt[b], 1);
        part[base[b] + r] = ((unsigned int)s << 8) | (unsigned int)(d & 255);
    }
}

// ==== p4: per-bucket rank -> row_start + srcs (ushort)
__global__ __launch_bounds__(256) void p4_fill_kernel(
    const unsigned int* __restrict__ part, const int* __restrict__ btot,
    int* __restrict__ row_start, unsigned short* __restrict__ srcs)
{
    __shared__ int t[256];
    __shared__ int deg[NPB];
    __shared__ int off[NPB];
    __shared__ int cnt[NPB];
    int tid = threadIdx.x;
    int b = blockIdx.x;
    int v = (tid < NBK) ? btot[tid] : 0;
    t[tid] = v;
    __syncthreads();
    for (int o = 1; o < 256; o <<= 1) {
        int u = (tid >= o) ? t[tid - o] : 0;
        __syncthreads();
        t[tid] += u;
        __syncthreads();
    }
    int hi = t[b];
    int lo = hi - btot[b];
    if (b == 0 && tid == 0) row_start[NN] = NE;
    deg[tid] = 0;
    cnt[tid] = 0;
    __syncthreads();
    for (int i = lo + tid; i < hi; i += 256)
        atomicAdd(&deg[part[i] & 255u], 1);
    __syncthreads();
    int dv = deg[tid];
    off[tid] = dv;
    __syncthreads();
    for (int o = 1; o < 256; o <<= 1) {
        int u = (tid >= o) ? off[tid - o] : 0;
        __syncthreads();
        off[tid] += u;
        __syncthreads();
    }
    int ex = off[tid] - dv;
    __syncthreads();
    off[tid] = ex;
    __syncthreads();
    int node = b * NPB + tid;
    if (node < NN) row_start[node] = lo + ex;
    for (int i = lo + tid; i < hi; i += 256) {
        unsigned int e = part[i];
        int n = (int)(e & 255u);
        int r = atomicAdd(&cnt[n], 1);
        srcs[lo + off[n] + r] = (unsigned short)(e >> 8);
    }
}

// ==== fused GAT layer-1 aggregation + micro-GEMM2 tail.
// 4 waves/block, 1 node/wave (grid = NN/4 = 12500: same occupancy profile as
// the standalone agg64). h1 rows stay in 1 KB LDS; z2/el2/er2 computed by
// 128 threads per block from the 4x64 tile (64 FMAs/thread, no VGPR blowup).
__global__ __launch_bounds__(256) void agg64_gemm2_kernel(
    const int* __restrict__ row_start, const unsigned short* __restrict__ srcs,
    const float* __restrict__ el, const float* __restrict__ er,
    const unsigned short* __restrict__ z1b, const float* __restrict__ b1,
    const float* __restrict__ W2, const float* __restrict__ al2,
    const float* __restrict__ ar2,
    unsigned short* __restrict__ z2b, float* __restrict__ el2, float* __restrict__ er2)
{
    __shared__ float Ws2[F1 * F2];   // 8 KB
    __shared__ float hs[4][F1];      // 1 KB
    int tid = threadIdx.x;

    {   // stage W2 (consumed only after the __syncthreads below)
        const float4* W4 = reinterpret_cast<const float4*>(W2);
        float4* Ws4 = reinterpret_cast<float4*>(Ws2);
        Ws4[tid] = W4[tid];
        Ws4[tid + 256] = W4[tid + 256];
    }

    int w = tid >> 6;
    int lane = tid & 63;
    int g = lane >> 4, c = lane & 15;
    int node = blockIdx.x * 4 + w;          // NN % 4 == 0: always valid
    int beg = row_start[node], end = row_start[node + 1];
    float erd = er[node];

    int i0 = beg + lane;
    float v0 = -INFINITY;
    if (i0 < end) v0 = lrelu(el[srcs[i0]] + erd, 0.2f);
    float lm = v0;
    for (int i = i0 + 64; i < end; i += 64)
        lm = fmaxf(lm, lrelu(el[srcs[i]] + erd, 0.2f));
    #pragma unroll
    for (int mm = 1; mm < 64; mm <<= 1) lm = fmaxf(lm, __shfl_xor(lm, mm));

    float preg = 0.f, ls = 0.f;
    if (i0 < end) { preg = __expf(v0 - lm); ls = preg; }
    for (int i = i0 + 64; i < end; i += 64)
        ls += __expf(lrelu(el[srcs[i]] + erd, 0.2f) - lm);
    #pragma unroll
    for (int mm = 1; mm < 64; mm <<= 1) ls += __shfl_xor(ls, mm);
    float inv_s = (ls > 0.f) ? 1.0f / ls : 0.f;
    preg *= inv_s;

    const ushort4* z4 = reinterpret_cast<const ushort4*>(z1b);
    float4 acc = {0.f, 0.f, 0.f, 0.f};
    int ib = beg;
    for (; ib + 8 <= end; ib += 8) {
        int ia = ib + g, ic = ib + 4 + g;
        int ja = ia - beg, jc = ic - beg;
        float aa = __shfl(preg, ja & 63);
        float ac = __shfl(preg, jc & 63);
        int sna = srcs[ia], snc = srcs[ic];
        if (ja >= 64) aa = __expf(lrelu(el[sna] + erd, 0.2f) - lm) * inv_s;
        if (jc >= 64) ac = __expf(lrelu(el[snc] + erd, 0.2f) - lm) * inv_s;
        ushort4 ua = z4[(size_t)sna * 16 + c];
        ushort4 uc = z4[(size_t)snc * 16 + c];
        acc.x = fmaf(aa, bf2f(ua.x), fmaf(ac, bf2f(uc.x), acc.x));
        acc.y = fmaf(aa, bf2f(ua.y), fmaf(ac, bf2f(uc.y), acc.y));
        acc.z = fmaf(aa, bf2f(ua.z), fmaf(ac, bf2f(uc.z), acc.z));
        acc.w = fmaf(aa, bf2f(ua.w), fmaf(ac, bf2f(uc.w), acc.w));
    }
    for (; ib < end; ib += 4) {
        int i = ib + g, jj = i - beg;
        float aa = __shfl(preg, jj & 63);
        if (i < end) {
            int sn = srcs[i];
            if (jj >= 64) aa = __expf(lrelu(el[sn] + erd, 0.2f) - lm) * inv_s;
            ushort4 u = z4[(size_t)sn * 16 + c];
            acc.x = fmaf(aa, bf2f(u.x), acc.x);
            acc.y = fmaf(aa, bf2f(u.y), acc.y);
            acc.z = fmaf(aa, bf2f(u.z), acc.z);
            acc.w = fmaf(aa, bf2f(u.w), acc.w);
        }
    }
    #pragma unroll
    for (int mm = 16; mm < 64; mm <<= 1) {
        acc.x += __shfl_xor(acc.x, mm);
        acc.y += __shfl_xor(acc.y, mm);
        acc.z += __shfl_xor(acc.z, mm);
        acc.w += __shfl_xor(acc.w, mm);
    }
    if (g == 0) {
        float4 bb = reinterpret_cast<const float4*>(b1)[c];
        float4 o;
        o.x = lrelu(acc.x + bb.x, 0.01f);
        o.y = lrelu(acc.y + bb.y, 0.01f);
        o.z = lrelu(acc.z + bb.z, 0.01f);
        o.w = lrelu(acc.w + bb.w, 0.01f);
        *reinterpret_cast<float4*>(&hs[w][c * 4]) = o;   // h1 row stays in LDS
    }
    __syncthreads();

    // ---- micro-GEMM2: 4x64 @ 64x32, threads 0..127 (row = t>>5, j = t&31)
    if (tid < 128) {
        int row = tid >> 5, j = tid & 31;
        float zacc = 0.f;
        #pragma unroll 8
        for (int k = 0; k < F1; ++k)
            zacc = fmaf(hs[row][k], Ws2[k * F2 + j], zacc);
        int onode = blockIdx.x * 4 + row;
        z2b[(size_t)onode * F2 + j] = f2bf(zacc);
        float pl = zacc * al2[j], pr = zacc * ar2[j];
        #pragma unroll
        for (int mm = 1; mm < 32; mm <<= 1) {
            pl += __shfl_xor(pl, mm);
            pr += __shfl_xor(pr, mm);
        }
        if (j == 0) { el2[onode] = pl; er2[onode] = pr; }
    }
}

// ==== GAT layer-2 aggregation (half-wave/node, bf16 z2, ushort srcs)
__global__ __launch_bounds__(256) void gat_agg32_kernel(
    const int* __restrict__ row_start, const unsigned short* __restrict__ srcs,
    const float* __restrict__ el, const float* __restrict__ er,
    const unsigned short* __restrict__ z2b, const float* __restrict__ b,
    float* __restrict__ out, float slope_out)
{
    int node = (blockIdx.x * 256 + threadIdx.x) >> 5;
    if (node >= NN) return;
    int sub = threadIdx.x & 31;
    int base = threadIdx.x & 32;
    int g = sub >> 3, c = sub & 7;
    int beg = row_start[node], end = row_start[node + 1];
    float erd = er[node];

    int i0 = beg + sub;
    float v0 = -INFINITY;
    if (i0 < end) v0 = lrelu(el[srcs[i0]] + erd, 0.2f);
    float lm = v0;
    for (int i = i0 + 32; i < end; i += 32)
        lm = fmaxf(lm, lrelu(el[srcs[i]] + erd, 0.2f));
    #pragma unroll
    for (int mm = 1; mm < 32; mm <<= 1) lm = fmaxf(lm, __shfl_xor(lm, mm));

    float preg = 0.f, ls = 0.f;
    if (i0 < end) { preg = __expf(v0 - lm); ls = preg; }
    for (int i = i0 + 32; i < end; i += 32)
        ls += __expf(lrelu(el[srcs[i]] + erd, 0.2f) - lm);
    #pragma unroll
    for (int mm = 1; mm < 32; mm <<= 1) ls += __shfl_xor(ls, mm);
    float inv_s = (ls > 0.f) ? 1.0f / ls : 0.f;
    preg *= inv_s;

    const ushort4* z4 = reinterpret_cast<const ushort4*>(z2b);
    float4 acc = {0.f, 0.f, 0.f, 0.f};
    int ib = beg;
    for (; ib + 8 <= end; ib += 8) {
        int ia = ib + g, ic = ib + 4 + g;
        int ja = ia - beg, jc = ic - beg;
        float aa = __shfl(preg, base | (ja & 31));
        float ac = __shfl(preg, base | (jc & 31));
        int sna = srcs[ia], snc = srcs[ic];
        if (ja >= 32) aa = __expf(lrelu(el[sna] + erd, 0.2f) - lm) * inv_s;
        if (jc >= 32) ac = __expf(lrelu(el[snc] + erd, 0.2f) - lm) * inv_s;
        ushort4 ua = z4[(size_t)sna * 8 + c];
        ushort4 uc = z4[(size_t)snc * 8 + c];
        acc.x = fmaf(aa, bf2f(ua.x), fmaf(ac, bf2f(uc.x), acc.x));
        acc.y = fmaf(aa, bf2f(ua.y), fmaf(ac, bf2f(uc.y), acc.y));
        acc.z = fmaf(aa, bf2f(ua.z), fmaf(ac, bf2f(uc.z), acc.z));
        acc.w = fmaf(aa, bf2f(ua.w), fmaf(ac, bf2f(uc.w), acc.w));
    }
    for (; ib < end; ib += 4) {
        int i = ib + g, jj = i - beg;
        float aa = __shfl(preg, base | (jj & 31));
        if (i < end) {
            int sn = srcs[i];
            if (jj >= 32) aa = __expf(lrelu(el[sn] + erd, 0.2f) - lm) * inv_s;
            ushort4 u = z4[(size_t)sn * 8 + c];
            acc.x = fmaf(aa, bf2f(u.x), acc.x);
            acc.y = fmaf(aa, bf2f(u.y), acc.y);
            acc.z = fmaf(aa, bf2f(u.z), acc.z);
            acc.w = fmaf(aa, bf2f(u.w), acc.w);
        }
    }
    #pragma unroll
    for (int mm = 8; mm < 32; mm <<= 1) {
        acc.x += __shfl_xor(acc.x, mm);
        acc.y += __shfl_xor(acc.y, mm);
        acc.z += __shfl_xor(acc.z, mm);
        acc.w += __shfl_xor(acc.w, mm);
    }
    if (g == 0) {
        float4 bb = reinterpret_cast<const float4*>(b)[c];
        float4 o;
        o.x = lrelu(acc.x + bb.x, slope_out);
        o.y = lrelu(acc.y + bb.y, slope_out);
        o.z = lrelu(acc.z + bb.z, slope_out);
        o.w = lrelu(acc.w + bb.w, slope_out);
        reinterpret_cast<float4*>(out)[(size_t)node * 8 + c] = o;
    }
}

// ==== per-graph mean pool (graph_id sorted); one block per graph
__global__ __launch_bounds__(256) void pool_kernel(
    const float* __restrict__ h2, const int* __restrict__ gid, float* __restrict__ out)
{
    int g = blockIdx.x;
    int lo = 0, hi = NN;
    while (lo < hi) { int mid = (lo + hi) >> 1; if (gid[mid] < g) lo = mid + 1; else hi = mid; }
    int start = lo;
    hi = NN;
    while (lo < hi) { int mid = (lo + hi) >> 1; if (gid[mid] < g + 1) lo = mid + 1; else hi = mid; }
    int end = lo;
    int f = threadIdx.x & 31, r = threadIdx.x >> 5;
    float acc = 0.f;
    for (int n = start + r; n < end; n += 8) acc += h2[(size_t)n * F2 + f];
    __shared__ float red[256];
    red[threadIdx.x] = acc;
    __syncthreads();
    for (int st = 128; st >= 32; st >>= 1) {
        if (threadIdx.x < st) red[threadIdx.x] += red[threadIdx.x + st];
        __syncthreads();
    }
    if (threadIdx.x < 32) {
        float cnt = (float)(end - start);
        out[g * F2 + threadIdx.x] = red[threadIdx.x] / fmaxf(cnt, 1.0f);
    }
}

extern "C" void kernel_launch(void* const* d_in, const int* in_sizes, int n_in,
                              void* d_out, int out_size, void* d_ws, size_t ws_size,
                              hipStream_t stream)
{
    const float* x   = (const float*)d_in[0];
    const int*   src = (const int*)d_in[1];
    const int*   dst = (const int*)d_in[2];
    const int*   gid = (const int*)d_in[3];
    const float* W1  = (const float*)d_in[4];
    const float* al1 = (const float*)d_in[5];
    const float* ar1 = (const float*)d_in[6];
    const float* b1  = (const float*)d_in[7];
    const float* W2  = (const float*)d_in[8];
    const float* al2 = (const float*)d_in[9];
    const float* ar2 = (const float*)d_in[10];
    const float* b2  = (const float*)d_in[11];
    float* out = (float*)d_out;

    float* ws = (float*)d_ws;
    unsigned short* z1b = (unsigned short*)ws;                    // NN*64 bf16 (NN*32 f)
    unsigned short* z2b = (unsigned short*)(ws + (size_t)NN * 32);// NN*32 bf16 (NN*16 f)
    float* h2   = ws + (size_t)NN * 32 + (size_t)NN * 16;         // NN*32 floats
    float* el   = h2 + (size_t)NN * F2;                           // NN
    float* er   = el + NN;                                        // NN
    float* el2  = er + NN;                                        // NN
    float* er2  = el2 + NN;                                       // NN
    int* row_start = (int*)(er2 + NN);                            // NN+1 (+1 pad)
    unsigned short* srcs = (unsigned short*)(row_start + NN + 2); // NE ushort (NE/2 ints)
    int* hist      = (int*)(srcs + NE);                           // NBK*NC
    int* btot      = hist + NBK * NC;                             // NBK (+2 pad)
    unsigned int* part = (unsigned int*)(btot + NBK + 2);         // NE uint32

    // d1: per-chunk histogram (blocks 0..NC-1) || GEMM1 (blocks NC..)
    k1_hist_gemm1_kernel<<<NC + NTILE1, 256, 0, stream>>>(
        dst, hist, x, W1, al1, ar1, z1b, el, er);
    // d2: per-bucket exclusive scan over chunks
    p2a_scan_kernel<<<NBK, 256, 0, stream>>>(hist, btot);
    // d3: partition into bucket-contiguous packed entries
    p3_part_kernel<<<NC, 256, 0, stream>>>(src, dst, hist, btot, part);
    // d4: per-bucket rank -> row_start + srcs (ushort)
    p4_fill_kernel<<<NBK, 256, 0, stream>>>(part, btot, row_start, srcs);
    // d5: fused GAT layer-1 aggregation + micro-GEMM2 (h1 never leaves LDS)
    agg64_gemm2_kernel<<<NN / 4, 256, 0, stream>>>(
        row_start, srcs, el, er, z1b, b1, W2, al2, ar2, z2b, el2, er2);
    // d6: GAT layer-2 aggregation
    gat_agg32_kernel<<<(NN * 32 + 255) / 256, 256, 0, stream>>>(
        row_start, srcs, el2, er2, z2b, b2, h2, 0.01f);
    // d7: per-graph mean pool
    pool_kernel<<<NG, 256, 0, stream>>>(h2, gid, out);
}